// Round 1
// baseline (813.906 us; speedup 1.0000x reference)
//
#include <hip/hip_runtime.h>

#define N_SAMPLES 4096
#define DCOUNT 32
#define DIM 16
#define NSWEEP 10

static __device__ __forceinline__ float2 cmul(float2 a, float2 b) {
    return make_float2(a.x*b.x - a.y*b.y, a.x*b.y + a.y*b.x);
}
static __device__ __forceinline__ float2 cadd(float2 a, float2 b) {
    return make_float2(a.x + b.x, a.y + b.y);
}
static __device__ __forceinline__ float2 cconj(float2 a) {
    return make_float2(a.x, -a.y);
}

// ---------------------------------------------------------------------------
// Precompute per-d constants:
//   W_d  = A_d A_d^H            (16x16 complex)
//   S_d  = A_d + A_d^H          (16x16 complex)
//   cA_d [j] = sum_i A_d[i,j]   (column sums of A)
//   cA2_d[j] = sum_i (A_d@A_d)[i,j]
// ---------------------------------------------------------------------------
__global__ __launch_bounds__(256) void precompute_kernel(
    const float* __restrict__ Ar, const float* __restrict__ Ai,
    float2* __restrict__ S, float2* __restrict__ W,
    float2* __restrict__ cA, float2* __restrict__ cA2)
{
    const int d = blockIdx.x;     // 0..31
    const int t = threadIdx.x;    // 0..255
    const int i = t >> 4, j = t & 15;
    __shared__ float ar[16][16], ai[16][16], a2r[16][16], a2i[16][16];
    ar[i][j] = Ar[d*256 + t];
    ai[i][j] = Ai[d*256 + t];
    __syncthreads();
    float a2re = 0.f, a2im = 0.f, wre = 0.f, wim = 0.f;
    for (int k = 0; k < 16; ++k) {
        float xr = ar[i][k], xi = ai[i][k];
        // A2 = A @ A
        a2re += xr*ar[k][j] - xi*ai[k][j];
        a2im += xr*ai[k][j] + xi*ar[k][j];
        // W = A A^H : A[i,k] * conj(A[j,k])
        wre += xr*ar[j][k] + xi*ai[j][k];
        wim += xi*ar[j][k] - xr*ai[j][k];
    }
    S[d*256 + t] = make_float2(ar[i][j] + ar[j][i], ai[i][j] - ai[j][i]);
    W[d*256 + t] = make_float2(wre, wim);
    a2r[i][j] = a2re; a2i[i][j] = a2im;
    __syncthreads();
    if (t < 16) {   // column sums over i for column t
        float sr = 0.f, si = 0.f, s2r = 0.f, s2i = 0.f;
        for (int ii = 0; ii < 16; ++ii) {
            sr  += ar[ii][t];  si  += ai[ii][t];
            s2r += a2r[ii][t]; s2i += a2i[ii][t];
        }
        cA [d*16 + t] = make_float2(sr,  si);
        cA2[d*16 + t] = make_float2(s2r, s2i);
    }
}

// ---------------------------------------------------------------------------
// Per-sample: build H_n, Jacobi-diagonalize (parallel round-robin ordering),
// take eigvec of min eigenvalue, accumulate loss contribution.
// One matrix per 64-thread (single-wave) block; 4 elements per thread.
// ---------------------------------------------------------------------------
__global__ __launch_bounds__(64) void energy_kernel(
    const float* __restrict__ X,
    const float2* __restrict__ S, const float2* __restrict__ W,
    const float2* __restrict__ cA, const float2* __restrict__ cA2,
    float* __restrict__ out)
{
    const int n = blockIdx.x;
    const int t = threadIdx.x;   // 0..63

    __shared__ float2 H[256];
    __shared__ float2 V[256];
    __shared__ float  xv[32];
    __shared__ float2 cS[16], cO[16];
    __shared__ int    prt[16];
    __shared__ float  sdiag;
    __shared__ int    minIdx;

    if (t < 32) xv[t] = X[n*DCOUNT + t];
    __syncthreads();
    if (t == 0) {
        float s = 0.f;
        for (int d = 0; d < DCOUNT; ++d) s += xv[d]*xv[d];
        sdiag = 0.5f*s + 1e-5f;
    }
    __syncthreads();

    // Build H_n = 0.5 * sum_d (W_d - x_d S_d)  (+ (0.5*sum x^2 + eps) on diag)
    {
        float2 nh[4], nv[4];
        for (int u = 0; u < 4; ++u) {
            int e = t*4 + u;
            int i = e >> 4, j = e & 15;
            float hr = 0.f, hi = 0.f;
            for (int d = 0; d < DCOUNT; ++d) {
                float2 w = W[d*256 + e];
                float2 s = S[d*256 + e];
                float  x = xv[d];
                hr += w.x - x*s.x;
                hi += w.y - x*s.y;
            }
            hr *= 0.5f; hi *= 0.5f;
            if (i == j) hr += sdiag;
            nh[u] = make_float2(hr, hi);
            nv[u] = make_float2(i == j ? 1.f : 0.f, 0.f);
        }
        for (int u = 0; u < 4; ++u) { H[t*4+u] = nh[u]; V[t*4+u] = nv[u]; }
    }
    __syncthreads();

    // Parallel-ordering cyclic Jacobi
    for (int sw = 0; sw < NSWEEP; ++sw) {
        for (int r = 0; r < 15; ++r) {
            if (t < 8) {
                int p, q;
                if (t == 0) { p = 15; q = r; }
                else { p = (r + t) % 15; q = (r + 15 - t) % 15; }
                float a  = H[p*16 + p].x;
                float dd = H[q*16 + q].x;
                float2 b = H[p*16 + q];
                float ab = sqrtf(b.x*b.x + b.y*b.y);
                float c, s, er, ei;
                if (ab < 1e-30f) {
                    c = 1.f; s = 0.f; er = 1.f; ei = 0.f;
                } else {
                    er = b.x / ab; ei = b.y / ab;
                    float tau = (dd - a) / (2.f * ab);
                    float tt = 1.f / (fabsf(tau) + sqrtf(1.f + tau*tau));
                    if (tau < 0.f) tt = -tt;
                    c = 1.f / sqrtf(1.f + tt*tt);
                    s = tt * c;
                }
                prt[p] = q; prt[q] = p;
                // J column p: (c, -s e^{-i phi}); column q: (s, c e^{-i phi})
                cS[p] = make_float2(c, 0.f);
                cO[p] = make_float2(-s*er,  s*ei);
                cS[q] = make_float2( c*er, -c*ei);
                cO[q] = make_float2(s, 0.f);
            }
            __syncthreads();

            // Column phase: H <- H*J, V <- V*J
            float2 nh[4], nv[4];
            for (int u = 0; u < 4; ++u) {
                int e = t*4 + u;
                int i = e >> 4, j = e & 15;
                int pj = prt[j];
                float2 a0 = H[i*16 + j],  a1 = H[i*16 + pj];
                float2 v0 = V[i*16 + j],  v1 = V[i*16 + pj];
                float2 csj = cS[j], coj = cO[j];
                nh[u] = cadd(cmul(csj, a0), cmul(coj, a1));
                nv[u] = cadd(cmul(csj, v0), cmul(coj, v1));
            }
            __syncthreads();
            for (int u = 0; u < 4; ++u) { H[t*4+u] = nh[u]; V[t*4+u] = nv[u]; }
            __syncthreads();

            // Row phase: H <- J^H * H
            for (int u = 0; u < 4; ++u) {
                int e = t*4 + u;
                int i = e >> 4, j = e & 15;
                int pi = prt[i];
                float2 a0 = H[i*16 + j], a1 = H[pi*16 + j];
                float2 csi = cconj(cS[i]), coi = cconj(cO[i]);
                nh[u] = cadd(cmul(csi, a0), cmul(coi, a1));
            }
            __syncthreads();
            for (int u = 0; u < 4; ++u) H[t*4+u] = nh[u];
            __syncthreads();
        }
    }

    // argmin of diagonal
    if (t == 0) {
        float best = H[0].x; int bi = 0;
        for (int m = 1; m < 16; ++m) {
            float v = H[m*17].x;
            if (v < best) { best = v; bi = m; }
        }
        minIdx = bi;
    }
    __syncthreads();
    const int mi = minIdx;

    // Loss epilogue: lanes 0..31 each handle one d.
    float contrib = 0.f;
    if (t < 32) {
        float tr = 0.f, ti = 0.f;
        float2 psi[16];
        for (int j = 0; j < 16; ++j) {
            psi[j] = V[j*16 + mi];
            tr += psi[j].x; ti += psi[j].y;
        }
        float zr = 0.f, zi = 0.f, z2r = 0.f, z2i = 0.f;
        for (int j = 0; j < 16; ++j) {
            float2 cj  = cA [t*16 + j];
            float2 c2j = cA2[t*16 + j];
            zr  += cj.x*psi[j].x  - cj.y*psi[j].y;
            zi  += cj.x*psi[j].y  + cj.y*psi[j].x;
            z2r += c2j.x*psi[j].x - c2j.y*psi[j].y;
            z2i += c2j.x*psi[j].y + c2j.y*psi[j].x;
        }
        // pos = Re[z * conj(tsum)], e2 = Re[z2 * conj(tsum)]
        float pos = zr*tr + zi*ti;
        float e2  = z2r*tr + z2i*ti;
        float dx  = pos - xv[t];
        contrib = dx*dx + 0.1f*(e2 - pos*pos);
    }
    for (int off = 32; off > 0; off >>= 1)
        contrib += __shfl_down(contrib, off);
    if (t == 0) atomicAdd(out, contrib * (1.0f/(float)N_SAMPLES));
}

extern "C" void kernel_launch(void* const* d_in, const int* in_sizes, int n_in,
                              void* d_out, int out_size, void* d_ws, size_t ws_size,
                              hipStream_t stream)
{
    const float* A_real = (const float*)d_in[0];   // 32*16*16
    const float* A_imag = (const float*)d_in[1];   // 32*16*16
    const float* X      = (const float*)d_in[2];   // 4096*32
    float* out = (float*)d_out;

    // workspace layout (float2 elements)
    float2* S   = (float2*)d_ws;          // 32*256
    float2* W   = S  + DCOUNT*256;        // 32*256
    float2* cA  = W  + DCOUNT*256;        // 32*16
    float2* cA2 = cA + DCOUNT*16;         // 32*16
    (void)in_sizes; (void)n_in; (void)out_size; (void)ws_size;

    hipMemsetAsync(d_out, 0, sizeof(float), stream);
    precompute_kernel<<<DCOUNT, 256, 0, stream>>>(A_real, A_imag, S, W, cA, cA2);
    energy_kernel<<<N_SAMPLES, 64, 0, stream>>>(X, S, W, cA, cA2, out);
}

// Round 4
// 571.517 us; speedup vs baseline: 1.4241x; 1.4241x over previous
//
#include <hip/hip_runtime.h>

#define NS 4096
#define DC 32
#define NROUND 150   // 10 sweeps x 15 rounds (R1-proven count)

static __device__ __forceinline__ float2 cmul(float2 a, float2 b) {
    return make_float2(a.x*b.x - a.y*b.y, a.x*b.y + a.y*b.x);
}
static __device__ __forceinline__ float2 cadd(float2 a, float2 b) {
    return make_float2(a.x + b.x, a.y + b.y);
}
static __device__ __forceinline__ float2 cconj(float2 a) {
    return make_float2(a.x, -a.y);
}

#define SWZ(r_, c_) (((r_) << 4) | (((c_) + (r_)) & 15))

// partner / pivot-id / role for index c in round rr (R1 pair schedule:
// pairs are (15, rr) and ((rr+t)%15, (rr+15-t)%15) for t=1..7).
static __device__ __forceinline__ void pairinfo(int c, int rr,
                                                int &pc, int &pid, bool &isP)
{
    if (c == 15) { pc = rr; pid = 0; isP = true; return; }
    int m = c - rr; if (m < 0) m += 15;
    if (m == 0) { pc = 15; pid = 0; isP = false; return; }
    int tw = 2*rr - c;
    if (tw < 0)   tw += 15;
    if (tw >= 15) tw -= 15;
    pc = tw;
    if (m <= 7) { pid = m;      isP = true;  }
    else        { pid = 15 - m; isP = false; }
}

// ---------------------------------------------------------------------------
// P1 (R1-verbatim): W_d = A_d A_d^H, S_d = A_d + A_d^H, column sums of A, A^2.
// ---------------------------------------------------------------------------
__global__ __launch_bounds__(256) void precompute_kernel(
    const float* __restrict__ Ar, const float* __restrict__ Ai,
    float2* __restrict__ S, float2* __restrict__ W,
    float2* __restrict__ cA, float2* __restrict__ cA2)
{
    const int d = blockIdx.x;
    const int t = threadIdx.x;
    const int i = t >> 4, j = t & 15;
    __shared__ float ar[16][16], ai[16][16], a2r[16][16], a2i[16][16];
    ar[i][j] = Ar[d*256 + t];
    ai[i][j] = Ai[d*256 + t];
    __syncthreads();
    float a2re = 0.f, a2im = 0.f, wre = 0.f, wim = 0.f;
    for (int k = 0; k < 16; ++k) {
        float xr = ar[i][k], xi = ai[i][k];
        a2re += xr*ar[k][j] - xi*ai[k][j];
        a2im += xr*ai[k][j] + xi*ar[k][j];
        wre += xr*ar[j][k] + xi*ai[j][k];
        wim += xi*ar[j][k] - xr*ai[j][k];
    }
    S[d*256 + t] = make_float2(ar[i][j] + ar[j][i], ai[i][j] - ai[j][i]);
    W[d*256 + t] = make_float2(wre, wim);
    a2r[i][j] = a2re; a2i[i][j] = a2im;
    __syncthreads();
    if (t < 16) {
        float sr = 0.f, si = 0.f, s2r = 0.f, s2i = 0.f;
        for (int ii = 0; ii < 16; ++ii) {
            sr  += ar[ii][t];  si  += ai[ii][t];
            s2r += a2r[ii][t]; s2i += a2i[ii][t];
        }
        cA [d*16 + t] = make_float2(sr,  si);
        cA2[d*16 + t] = make_float2(s2r, s2i);
    }
}

// ---------------------------------------------------------------------------
// Fused single-phase cyclic Jacobi (R1 math, ping-pong LDS, swizzled layout).
// Lane t: row i = t>>2, cols jb..jb+3 where jb = (t&3)*4  (elements 4t..4t+3).
// ---------------------------------------------------------------------------
__global__ __launch_bounds__(64) void energy_kernel(
    const float* __restrict__ X,
    const float2* __restrict__ S, const float2* __restrict__ W,
    const float2* __restrict__ cA, const float2* __restrict__ cA2,
    float* __restrict__ out)
{
    const int n = blockIdx.x;
    const int t = threadIdx.x;
    const int i  = t >> 2;
    const int jb = (t & 3) * 4;

    __shared__ float2 Ha[256], Hb[256], Va[256], Vb[256];
    __shared__ float4 coef[8];
    __shared__ float  xS[32];
    __shared__ float  diagS[16];
    __shared__ float2 psiS[16];
    __shared__ int    midxS;

    const float* Xn = X + n*DC;
    if (t < 32) xS[t] = Xn[t];

    // ---- build H (R1-exact arithmetic): elements e0..e0+3 ----
    {
        const int e0 = t*4;
        float hr[4] = {0.f,0.f,0.f,0.f}, hi[4] = {0.f,0.f,0.f,0.f};
        float sx2 = 0.f;
        for (int d = 0; d < DC; ++d) {
            float xd = Xn[d];
            sx2 += xd*xd;
            const float4* w4 = (const float4*)(W + d*256 + e0);
            const float4* s4 = (const float4*)(S + d*256 + e0);
            float4 wa = w4[0], wb = w4[1];
            float4 sa = s4[0], sb = s4[1];
            hr[0] += wa.x - xd*sa.x;  hi[0] += wa.y - xd*sa.y;
            hr[1] += wa.z - xd*sa.z;  hi[1] += wa.w - xd*sa.w;
            hr[2] += wb.x - xd*sb.x;  hi[2] += wb.y - xd*sb.y;
            hr[3] += wb.z - xd*sb.z;  hi[3] += wb.w - xd*sb.w;
        }
        float sdiag = 0.5f*sx2 + 1e-5f;
        #pragma unroll
        for (int u = 0; u < 4; ++u) {
            int j = jb + u;
            float re = 0.5f*hr[u], im = 0.5f*hi[u];
            if (i == j) re += sdiag;
            Ha[SWZ(i,j)] = make_float2(re, im);
            Va[SWZ(i,j)] = make_float2(i == j ? 1.f : 0.f, 0.f);
        }
    }
    __syncthreads();

    // ---- fused Jacobi rounds ----
    float2 *hc = Ha, *hn = Hb, *vc = Va, *vn = Vb;
    int rr = 0;
    for (int r = 0; r < NROUND; ++r) {
        // pivots (lanes 0..7) -> coef[]
        if (t < 8) {
            int p, q;
            if (t == 0) { p = 15; q = rr; }
            else {
                p = rr + t;      if (p >= 15) p -= 15;
                q = rr + 15 - t; if (q >= 15) q -= 15;
            }
            float a  = hc[SWZ(p,p)].x;
            float dd = hc[SWZ(q,q)].x;
            float2 b = hc[SWZ(p,q)];
            float ab = sqrtf(b.x*b.x + b.y*b.y);
            float c_, s_, er, ei;
            if (ab < 1e-30f) {
                c_ = 1.f; s_ = 0.f; er = 1.f; ei = 0.f;
            } else {
                er = b.x / ab; ei = b.y / ab;
                float tau = (dd - a) / (2.f * ab);
                float tt = 1.f / (fabsf(tau) + sqrtf(1.f + tau*tau));
                if (tau < 0.f) tt = -tt;
                c_ = 1.f / sqrtf(1.f + tt*tt);
                s_ = tt * c_;
            }
            coef[t] = make_float4(c_, s_, er, ei);
        }
        __syncthreads();

        // row coefficients for row i (conjugated for row-side application)
        int   pi, pidi; bool rpI;
        pairinfo(i, rr, pi, pidi, rpI);
        float4 fi = coef[pidi];
        float2 csi, coi;
        if (rpI) { csi = make_float2(fi.x, 0.f);
                   coi = make_float2(-fi.y*fi.z,  fi.y*fi.w); }
        else     { csi = make_float2(fi.x*fi.z, -fi.x*fi.w);
                   coi = make_float2(fi.y, 0.f); }
        float2 csic = cconj(csi), coic = cconj(coi);

        const int bi  = i  << 4;
        const int bpi = pi << 4;

        #pragma unroll
        for (int u = 0; u < 4; ++u) {
            int j = jb + u;
            int pj, pidj; bool rpJ;
            pairinfo(j, rr, pj, pidj, rpJ);
            float4 fj = coef[pidj];
            float2 csj, coj;
            if (rpJ) { csj = make_float2(fj.x, 0.f);
                       coj = make_float2(-fj.y*fj.z,  fj.y*fj.w); }
            else     { csj = make_float2(fj.x*fj.z, -fj.x*fj.w);
                       coj = make_float2(fj.y, 0.f); }

            int aij  = bi  | ((j  + i)  & 15);
            int aipj = bi  | ((pj + i)  & 15);
            int apij = bpi | ((j  + pi) & 15);
            int apipj= bpi | ((pj + pi) & 15);

            float2 hij  = hc[aij],  hipj  = hc[aipj];
            float2 hpij = hc[apij], hpipj = hc[apipj];
            float2 top = cadd(cmul(csj, hij),  cmul(coj, hipj));
            float2 bot = cadd(cmul(csj, hpij), cmul(coj, hpipj));
            hn[aij] = cadd(cmul(csic, top), cmul(coic, bot));

            float2 vij = vc[aij], vipj = vc[aipj];
            vn[aij] = cadd(cmul(csj, vij), cmul(coj, vipj));
        }
        __syncthreads();

        float2* tmp;
        tmp = hc; hc = hn; hn = tmp;
        tmp = vc; vc = vn; vn = tmp;
        rr = (rr == 14) ? 0 : rr + 1;
    }

    // ---- diag argmin + eigvec extraction ----
    if (t < 16) diagS[t] = hc[SWZ(t,t)].x;
    __syncthreads();
    if (t == 0) {
        float best = diagS[0]; int bi_ = 0;
        for (int m = 1; m < 16; ++m) {
            float v = diagS[m];
            if (v < best) { best = v; bi_ = m; }
        }
        midxS = bi_;
    }
    __syncthreads();
    {
        const int mi = midxS;
        if (t < 16) psiS[t] = vc[SWZ(t, mi)];
    }
    __syncthreads();

    // ---- loss epilogue (R1-verbatim): lanes 0..31 each handle one d ----
    float contrib = 0.f;
    if (t < 32) {
        float tr = 0.f, ti = 0.f;
        float2 psi[16];
        for (int jj = 0; jj < 16; ++jj) {
            psi[jj] = psiS[jj];
            tr += psi[jj].x; ti += psi[jj].y;
        }
        float zr = 0.f, zi = 0.f, z2r = 0.f, z2i = 0.f;
        for (int jj = 0; jj < 16; ++jj) {
            float2 cj  = cA [t*16 + jj];
            float2 c2j = cA2[t*16 + jj];
            zr  += cj.x*psi[jj].x  - cj.y*psi[jj].y;
            zi  += cj.x*psi[jj].y  + cj.y*psi[jj].x;
            z2r += c2j.x*psi[jj].x - c2j.y*psi[jj].y;
            z2i += c2j.x*psi[jj].y + c2j.y*psi[jj].x;
        }
        float pos = zr*tr + zi*ti;
        float e2  = z2r*tr + z2i*ti;
        float dx  = pos - xS[t];
        contrib = dx*dx + 0.1f*(e2 - pos*pos);
    }
    for (int off = 32; off > 0; off >>= 1)
        contrib += __shfl_down(contrib, off);
    if (t == 0) atomicAdd(out, contrib * (1.0f/(float)NS));
}

extern "C" void kernel_launch(void* const* d_in, const int* in_sizes, int n_in,
                              void* d_out, int out_size, void* d_ws, size_t ws_size,
                              hipStream_t stream)
{
    const float* A_real = (const float*)d_in[0];
    const float* A_imag = (const float*)d_in[1];
    const float* X      = (const float*)d_in[2];
    float* out = (float*)d_out;

    float2* S   = (float2*)d_ws;          // 32*256
    float2* W   = S  + DC*256;            // 32*256
    float2* cA  = W  + DC*256;            // 32*16
    float2* cA2 = cA + DC*16;             // 32*16
    (void)in_sizes; (void)n_in; (void)out_size; (void)ws_size;

    hipMemsetAsync(d_out, 0, sizeof(float), stream);
    precompute_kernel<<<DC, 256, 0, stream>>>(A_real, A_imag, S, W, cA, cA2);
    energy_kernel<<<NS, 64, 0, stream>>>(X, S, W, cA, cA2, out);
}

// Round 6
// 302.067 us; speedup vs baseline: 2.6945x; 1.8920x over previous
//
#include <hip/hip_runtime.h>

#define NS 4096
#define DC 32
#define MAXCHK 7     // checks every 2 sweeps -> cap = 14 sweeps

static __device__ __forceinline__ float2 cmul(float2 a, float2 b) {
    return make_float2(a.x*b.x - a.y*b.y, a.x*b.y + a.y*b.x);
}
static __device__ __forceinline__ float2 cadd(float2 a, float2 b) {
    return make_float2(a.x + b.x, a.y + b.y);
}

// XOR diagonal swizzle: conflict-spreading, 1-op dynamic addressing.
#define IDX(r_, c_) (((r_) << 4) | ((c_) ^ (r_)))

// ---------------------------------------------------------------------------
// P1 (R1-verbatim): W_d = A_d A_d^H, S_d = A_d + A_d^H, column sums of A, A^2.
// ---------------------------------------------------------------------------
__global__ __launch_bounds__(256) void precompute_kernel(
    const float* __restrict__ Ar, const float* __restrict__ Ai,
    float2* __restrict__ S, float2* __restrict__ W,
    float2* __restrict__ cA, float2* __restrict__ cA2)
{
    const int d = blockIdx.x;
    const int t = threadIdx.x;
    const int i = t >> 4, j = t & 15;
    __shared__ float ar[16][16], ai[16][16], a2r[16][16], a2i[16][16];
    ar[i][j] = Ar[d*256 + t];
    ai[i][j] = Ai[d*256 + t];
    __syncthreads();
    float a2re = 0.f, a2im = 0.f, wre = 0.f, wim = 0.f;
    for (int k = 0; k < 16; ++k) {
        float xr = ar[i][k], xi = ai[i][k];
        a2re += xr*ar[k][j] - xi*ai[k][j];
        a2im += xr*ai[k][j] + xi*ar[k][j];
        wre += xr*ar[j][k] + xi*ai[j][k];
        wim += xi*ar[j][k] - xr*ai[j][k];
    }
    S[d*256 + t] = make_float2(ar[i][j] + ar[j][i], ai[i][j] - ai[j][i]);
    W[d*256 + t] = make_float2(wre, wim);
    a2r[i][j] = a2re; a2i[i][j] = a2im;
    __syncthreads();
    if (t < 16) {
        float sr = 0.f, si = 0.f, s2r = 0.f, s2i = 0.f;
        for (int ii = 0; ii < 16; ++ii) {
            sr  += ar[ii][t];  si  += ai[ii][t];
            s2r += a2r[ii][t]; s2i += a2i[ii][t];
        }
        cA [d*16 + t] = make_float2(sr,  si);
        cA2[d*16 + t] = make_float2(s2r, s2i);
    }
}

// ---------------------------------------------------------------------------
// Fused cyclic Jacobi: table-driven coefficients, static ping-pong LDS,
// sweep-level convergence gate. Lane t: row i = t>>2, cols jb..jb+3.
// ---------------------------------------------------------------------------
__global__ __launch_bounds__(64) void energy_kernel(
    const float* __restrict__ X,
    const float2* __restrict__ S, const float2* __restrict__ W,
    const float2* __restrict__ cA, const float2* __restrict__ cA2,
    float* __restrict__ out)
{
    const int n = blockIdx.x;
    const int t = threadIdx.x;
    const int i  = t >> 2;
    const int jb = (t & 3) * 4;

    __shared__ float2 Ha[256], Hb[256], Va[256], Vb[256];
    __shared__ float4 csco[16];   // (cs.x, cs.y, co.x, co.y) per column
    __shared__ int    prt[16];    // partner column
    __shared__ float  xS[32];
    __shared__ float  diagS[16];
    __shared__ float2 psiS[16];
    __shared__ int    midxS;

    const float* Xn = X + n*DC;
    if (t < 32) xS[t] = Xn[t];

    const int aij0 = IDX(i, jb),   aij1 = IDX(i, jb+1);
    const int aij2 = IDX(i, jb+2), aij3 = IDX(i, jb+3);
    const int am[4] = {aij0, aij1, aij2, aij3};

    // ---- build H (R1-exact arithmetic) + Frobenius norm for the gate ----
    float tol2;
    {
        const int e0 = t*4;
        float hr[4] = {0.f,0.f,0.f,0.f}, hi[4] = {0.f,0.f,0.f,0.f};
        float sx2 = 0.f;
        for (int d = 0; d < DC; ++d) {
            float xd = Xn[d];
            sx2 += xd*xd;
            const float4* w4 = (const float4*)(W + d*256 + e0);
            const float4* s4 = (const float4*)(S + d*256 + e0);
            float4 wa = w4[0], wb = w4[1];
            float4 sa = s4[0], sb = s4[1];
            hr[0] += wa.x - xd*sa.x;  hi[0] += wa.y - xd*sa.y;
            hr[1] += wa.z - xd*sa.z;  hi[1] += wa.w - xd*sa.w;
            hr[2] += wb.x - xd*sb.x;  hi[2] += wb.y - xd*sb.y;
            hr[3] += wb.z - xd*sb.z;  hi[3] += wb.w - xd*sb.w;
        }
        float sdiag = 0.5f*sx2 + 1e-5f;
        float nf = 0.f;
        #pragma unroll
        for (int u = 0; u < 4; ++u) {
            int j = jb + u;
            float re = 0.5f*hr[u], im = 0.5f*hi[u];
            if (i == j) re += sdiag;
            nf += re*re + im*im;
            Ha[am[u]] = make_float2(re, im);
            Va[am[u]] = make_float2(i == j ? 1.f : 0.f, 0.f);
        }
        #pragma unroll
        for (int m = 1; m < 64; m <<= 1) nf += __shfl_xor(nf, m);
        tol2 = 1e-11f * nf;
    }
    __syncthreads();

    int rr = 0;

    // pivot: lanes 0..7 compute rotation for their pair (R4-exact math)
    auto pivot = [&](const float2* hc) {
        if (t < 8) {
            int p, q;
            if (t == 0) { p = 15; q = rr; }
            else {
                p = rr + t;      if (p >= 15) p -= 15;
                q = rr + 15 - t; if (q >= 15) q -= 15;
            }
            float a  = hc[p << 4].x;
            float dd = hc[q << 4].x;
            float2 b = hc[(p << 4) | (q ^ p)];
            float ab = sqrtf(b.x*b.x + b.y*b.y);
            float c_, s_, er, ei;
            if (ab < 1e-30f) {
                c_ = 1.f; s_ = 0.f; er = 1.f; ei = 0.f;
            } else {
                er = b.x / ab; ei = b.y / ab;
                float tau = (dd - a) / (2.f * ab);
                float tt = 1.f / (fabsf(tau) + sqrtf(1.f + tau*tau));
                if (tau < 0.f) tt = -tt;
                c_ = 1.f / sqrtf(1.f + tt*tt);
                s_ = tt * c_;
            }
            csco[p] = make_float4(c_, 0.f, -s_*er, s_*ei);
            csco[q] = make_float4(c_*er, -c_*ei, s_, 0.f);
            prt[p] = q; prt[q] = p;
        }
    };

    // fused col+row update; returns per-lane off-diag |.|^2 if wantOff
    auto body = [&](const float2* hc, float2* hn,
                    const float2* vc, float2* vn, bool wantOff) -> float {
        float4 fi = csco[i];
        int    pi = prt[i];
        float2 csi = make_float2(fi.x, -fi.y);
        float2 coi = make_float2(fi.z, -fi.w);
        const int rbase = i << 4, pbase = pi << 4;
        float off2 = 0.f;
        #pragma unroll
        for (int u = 0; u < 4; ++u) {
            const int j   = jb + u;
            const int aij = am[u];
            float4 fj = csco[j];
            int    pj = prt[j];
            float2 csj = make_float2(fj.x, fj.y);
            float2 coj = make_float2(fj.z, fj.w);
            const int aipj  = rbase | (pj ^ i);
            const int apij  = pbase | (j  ^ pi);
            const int apipj = pbase | (pj ^ pi);

            float2 hij  = hc[aij],  hipj  = hc[aipj];
            float2 hpij = hc[apij], hpipj = hc[apipj];
            float2 top = cadd(cmul(csj, hij),  cmul(coj, hipj));
            float2 bot = cadd(cmul(csj, hpij), cmul(coj, hpipj));
            float2 res = cadd(cmul(csi, top), cmul(coi, bot));
            hn[aij] = res;
            if (wantOff && j != i) off2 += res.x*res.x + res.y*res.y;

            float2 vij = vc[aij], vipj = vc[aipj];
            vn[aij] = cadd(cmul(csj, vij), cmul(coj, vipj));
        }
        return off2;
    };

    // ---- gated sweep loop: 2 rounds/iter, check every 15 iters (2 sweeps) --
    int iter = 0, chkcd = 15;
    for (;;) {
        const bool chk = (chkcd == 1);
        pivot(Ha);
        __syncthreads();
        body(Ha, Hb, Va, Vb, false);
        __syncthreads();
        rr = (rr == 14) ? 0 : rr + 1;
        pivot(Hb);
        __syncthreads();
        float off2 = body(Hb, Ha, Vb, Va, chk);
        __syncthreads();
        rr = (rr == 14) ? 0 : rr + 1;
        ++iter;
        if (chk) {
            #pragma unroll
            for (int m = 1; m < 64; m <<= 1) off2 += __shfl_xor(off2, m);
            if (off2 < tol2 || iter >= MAXCHK*15) break;
            chkcd = 15;
        } else {
            --chkcd;
        }
    }
    // even round count -> final H in Ha, V in Va

    // ---- diag argmin + eigvec extraction ----
    if (t < 16) diagS[t] = Ha[t << 4].x;
    __syncthreads();
    if (t == 0) {
        float best = diagS[0]; int bi_ = 0;
        for (int m = 1; m < 16; ++m) {
            float v = diagS[m];
            if (v < best) { best = v; bi_ = m; }
        }
        midxS = bi_;
    }
    __syncthreads();
    {
        const int mi = midxS;
        if (t < 16) psiS[t] = Va[(t << 4) | (mi ^ t)];
    }
    __syncthreads();

    // ---- loss epilogue (R1-verbatim) ----
    float contrib = 0.f;
    if (t < 32) {
        float tr = 0.f, ti = 0.f;
        float2 psi[16];
        for (int jj = 0; jj < 16; ++jj) {
            psi[jj] = psiS[jj];
            tr += psi[jj].x; ti += psi[jj].y;
        }
        float zr = 0.f, zi = 0.f, z2r = 0.f, z2i = 0.f;
        for (int jj = 0; jj < 16; ++jj) {
            float2 cj  = cA [t*16 + jj];
            float2 c2j = cA2[t*16 + jj];
            zr  += cj.x*psi[jj].x  - cj.y*psi[jj].y;
            zi  += cj.x*psi[jj].y  + cj.y*psi[jj].x;
            z2r += c2j.x*psi[jj].x - c2j.y*psi[jj].y;
            z2i += c2j.x*psi[jj].y + c2j.y*psi[jj].x;
        }
        float pos = zr*tr + zi*ti;
        float e2  = z2r*tr + z2i*ti;
        float dx  = pos - xS[t];
        contrib = dx*dx + 0.1f*(e2 - pos*pos);
    }
    for (int off = 32; off > 0; off >>= 1)
        contrib += __shfl_down(contrib, off);
    if (t == 0) atomicAdd(out, contrib * (1.0f/(float)NS));
}

extern "C" void kernel_launch(void* const* d_in, const int* in_sizes, int n_in,
                              void* d_out, int out_size, void* d_ws, size_t ws_size,
                              hipStream_t stream)
{
    const float* A_real = (const float*)d_in[0];
    const float* A_imag = (const float*)d_in[1];
    const float* X      = (const float*)d_in[2];
    float* out = (float*)d_out;

    float2* S   = (float2*)d_ws;          // 32*256
    float2* W   = S  + DC*256;            // 32*256
    float2* cA  = W  + DC*256;            // 32*16
    float2* cA2 = cA + DC*16;             // 32*16
    (void)in_sizes; (void)n_in; (void)out_size; (void)ws_size;

    hipMemsetAsync(d_out, 0, sizeof(float), stream);
    precompute_kernel<<<DC, 256, 0, stream>>>(A_real, A_imag, S, W, cA, cA2);
    energy_kernel<<<NS, 64, 0, stream>>>(X, S, W, cA, cA2, out);
}

// Round 7
// 191.692 us; speedup vs baseline: 4.2459x; 1.5758x over previous
//
#include <hip/hip_runtime.h>

#define NS 4096
#define DC 32
#define MAXIT2 104   // cap: 104 double-rounds = 208 rounds ~= 13.9 sweeps
#define CHKIV 8      // gate check every 8 double-rounds (16 rounds)

typedef float v2f __attribute__((ext_vector_type(2)));

static __device__ __forceinline__ v2f vswap(v2f b) {
    return __builtin_shufflevector(b, b, 1, 0);
}

// ---------------------------------------------------------------------------
// P1 (R1-verbatim): W_d = A_d A_d^H, S_d = A_d + A_d^H, column sums of A, A^2.
// ---------------------------------------------------------------------------
__global__ __launch_bounds__(256) void precompute_kernel(
    const float* __restrict__ Ar, const float* __restrict__ Ai,
    float2* __restrict__ S, float2* __restrict__ W,
    float2* __restrict__ cA, float2* __restrict__ cA2)
{
    const int d = blockIdx.x;
    const int t = threadIdx.x;
    const int i = t >> 4, j = t & 15;
    __shared__ float ar[16][16], ai[16][16], a2r[16][16], a2i[16][16];
    ar[i][j] = Ar[d*256 + t];
    ai[i][j] = Ai[d*256 + t];
    __syncthreads();
    float a2re = 0.f, a2im = 0.f, wre = 0.f, wim = 0.f;
    for (int k = 0; k < 16; ++k) {
        float xr = ar[i][k], xi = ai[i][k];
        a2re += xr*ar[k][j] - xi*ai[k][j];
        a2im += xr*ai[k][j] + xi*ar[k][j];
        wre += xr*ar[j][k] + xi*ai[j][k];
        wim += xi*ar[j][k] - xr*ai[j][k];
    }
    S[d*256 + t] = make_float2(ar[i][j] + ar[j][i], ai[i][j] - ai[j][i]);
    W[d*256 + t] = make_float2(wre, wim);
    a2r[i][j] = a2re; a2i[i][j] = a2im;
    __syncthreads();
    if (t < 16) {
        float sr = 0.f, si = 0.f, s2r = 0.f, s2i = 0.f;
        for (int ii = 0; ii < 16; ++ii) {
            sr  += ar[ii][t];  si  += ai[ii][t];
            s2r += a2r[ii][t]; s2i += a2i[ii][t];
        }
        cA [d*16 + t] = make_float2(sr,  si);
        cA2[d*16 + t] = make_float2(s2r, s2i);
    }
}

// ---------------------------------------------------------------------------
// Fused cyclic Jacobi: packed-f32 complex math, register-resident own
// elements (write-through), byte-addressed XOR-swizzled LDS, sweep gate.
// Lane t: row i = t>>2, cols jb..jb+3, jb = (t&3)*4.
// ---------------------------------------------------------------------------
__global__ __launch_bounds__(64) void energy_kernel(
    const float* __restrict__ X,
    const float2* __restrict__ S, const float2* __restrict__ W,
    const float2* __restrict__ cA, const float2* __restrict__ cA2,
    float* __restrict__ out)
{
    const int n = blockIdx.x;
    const int t = threadIdx.x;
    const int i  = t >> 2;
    const int jb = (t & 3) * 4;

    __shared__ v2f   Ha[256], Hb[256], Va[256], Vb[256];
    __shared__ float4 csco[16];
    __shared__ int    prtI[4];     // 16 packed bytes: prt[c] = partner<<3
    __shared__ float  xS[32];
    __shared__ float  diagS[16];
    __shared__ v2f    psiS[16];
    __shared__ int    midxS;

    const float* Xn = X + n*DC;
    if (t < 32) xS[t] = Xn[t];

    // hoisted byte-address constants (element byte = ((r<<4)|(c^r))<<3)
    const int i7 = i << 7, i3 = i << 3;
    const int shi = (i & 3) * 8;
    int amB[4], j3[4];
    #pragma unroll
    for (int u = 0; u < 4; ++u) {
        amB[u] = i7 | (((jb + u) ^ i) << 3);
        j3[u]  = (jb + u) << 3;
    }

    // ---- build H (R1-exact arithmetic, pk-vectorized) ----
    v2f h[4], v[4];
    float tol2;
    {
        const int e0 = t*4;
        v2f acc0 = {0.f,0.f}, acc1 = {0.f,0.f}, acc2 = {0.f,0.f}, acc3 = {0.f,0.f};
        float sx2 = 0.f;
        for (int d = 0; d < DC; ++d) {
            float xd = Xn[d];
            sx2 += xd*xd;
            const float4* w4 = (const float4*)(W + d*256 + e0);
            const float4* s4 = (const float4*)(S + d*256 + e0);
            float4 wa = w4[0], wb = w4[1];
            float4 sa = s4[0], sb = s4[1];
            v2f xv = {xd, xd};
            acc0 += (v2f){wa.x, wa.y} - xv * (v2f){sa.x, sa.y};
            acc1 += (v2f){wa.z, wa.w} - xv * (v2f){sa.z, sa.w};
            acc2 += (v2f){wb.x, wb.y} - xv * (v2f){sb.x, sb.y};
            acc3 += (v2f){wb.z, wb.w} - xv * (v2f){sb.z, sb.w};
        }
        float sdiag = 0.5f*sx2 + 1e-5f;
        v2f accs[4] = {acc0, acc1, acc2, acc3};
        float nf = 0.f;
        #pragma unroll
        for (int u = 0; u < 4; ++u) {
            int j = jb + u;
            v2f hv = 0.5f * accs[u];
            if (i == j) hv.x += sdiag;
            h[u] = hv;
            v[u] = (i == j) ? (v2f){1.f, 0.f} : (v2f){0.f, 0.f};
            nf += hv.x*hv.x + hv.y*hv.y;
            *(v2f*)((char*)Ha + amB[u]) = hv;
            *(v2f*)((char*)Va + amB[u]) = v[u];
        }
        #pragma unroll
        for (int m = 1; m < 64; m <<= 1) nf += __shfl_xor(nf, m);
        tol2 = 1e-10f * nf;
    }
    __syncthreads();

    int rr = 0;

    // pivot: lanes 0..7 compute rotation for their pair, publish tables
    auto pivot = [&](const v2f* hc) {
        if (t < 8) {
            int p, q;
            if (t == 0) { p = 15; q = rr; }
            else {
                p = rr + t;      if (p >= 15) p -= 15;
                q = rr + 15 - t; if (q >= 15) q -= 15;
            }
            float a  = (*(const v2f*)((const char*)hc + (p << 7))).x;
            float dd = (*(const v2f*)((const char*)hc + (q << 7))).x;
            v2f   b  = *(const v2f*)((const char*)hc + ((p << 7) | ((q ^ p) << 3)));
            float ab2 = b.x*b.x + b.y*b.y;
            float c_, s_, er, ei;
            if (ab2 > 1e-60f) {
                float abr = __builtin_amdgcn_rsqf(ab2);   // 1/|b|
                er = b.x * abr; ei = b.y * abr;
                float tau = (dd - a) * (0.5f * abr);
                float den = fabsf(tau) + sqrtf(1.f + tau*tau);
                float tt = __builtin_amdgcn_rcpf(den);
                tt = (tau < 0.f) ? -tt : tt;
                c_ = __builtin_amdgcn_rsqf(1.f + tt*tt);
                s_ = tt * c_;
            } else { c_ = 1.f; s_ = 0.f; er = 1.f; ei = 0.f; }
            // cS[p]=(c,0) cO[p]=(-s*er,s*ei) cS[q]=(c*er,-c*ei) cO[q]=(s,0)
            csco[p] = make_float4(c_, 0.f, -s_*er, s_*ei);
            csco[q] = make_float4(c_*er, -c_*ei, s_, 0.f);
            unsigned char* pb = (unsigned char*)prtI;
            pb[p] = (unsigned char)(q << 3);
            pb[q] = (unsigned char)(p << 3);
        }
    };

    // fused col+row round: hc->hn, vc->vn; own elements via h[]/v[] regs
    auto body = [&](const v2f* hc, v2f* hn, const v2f* vc, v2f* vn,
                    bool wantOff) -> float {
        float4 fi = csco[i];                       // row coeffs (conjugate)
        v2f cix = {fi.x, fi.x}, cir = {fi.y, -fi.y};
        v2f kix = {fi.z, fi.z}, kir = {fi.w, -fi.w};
        const int pib = (prtI[i >> 2] >> shi) & 255;   // pi<<3
        const int pi7 = pib << 4;                       // pi<<7
        const int wj  = prtI[t & 3];
        float off2 = 0.f;
        #pragma unroll
        for (int u = 0; u < 4; ++u) {
            float4 fj = csco[jb + u];
            v2f cjx = {fj.x, fj.x}, cjr = {-fj.y, fj.y};
            v2f kjx = {fj.z, fj.z}, kjr = {-fj.w, fj.w};
            const int pj3 = (wj >> (8*u)) & 255;        // pj<<3
            const int aipj  = i7  | (pj3   ^ i3);
            const int apij  = pi7 | (j3[u] ^ pib);
            const int apipj = pi7 | (pj3   ^ pib);

            v2f hij   = h[u];
            v2f hipj  = *(const v2f*)((const char*)hc + aipj);
            v2f hpij  = *(const v2f*)((const char*)hc + apij);
            v2f hpipj = *(const v2f*)((const char*)hc + apipj);

            v2f top = cjx*hij  + cjr*vswap(hij)  + kjx*hipj  + kjr*vswap(hipj);
            v2f bot = cjx*hpij + cjr*vswap(hpij) + kjx*hpipj + kjr*vswap(hpipj);
            v2f res = cix*top  + cir*vswap(top)  + kix*bot   + kir*vswap(bot);
            h[u] = res;
            *(v2f*)((char*)hn + amB[u]) = res;
            if (wantOff && (jb + u) != i) off2 += res.x*res.x + res.y*res.y;

            v2f vipj = *(const v2f*)((const char*)vc + aipj);
            v2f vres = cjx*v[u] + cjr*vswap(v[u]) + kjx*vipj + kjr*vswap(vipj);
            v[u] = vres;
            *(v2f*)((char*)vn + amB[u]) = vres;
        }
        return off2;
    };

    // ---- gated double-round loop ----
    int iter = 0, chkcd = CHKIV;
    for (;;) {
        const bool chk = (chkcd == 1);
        pivot(Ha);
        __syncthreads();
        body(Ha, Hb, Va, Vb, false);
        __syncthreads();
        rr = (rr == 14) ? 0 : rr + 1;
        pivot(Hb);
        __syncthreads();
        float off2 = body(Hb, Ha, Vb, Va, chk);
        __syncthreads();
        rr = (rr == 14) ? 0 : rr + 1;
        ++iter;
        if (chk) {
            #pragma unroll
            for (int m = 1; m < 64; m <<= 1) off2 += __shfl_xor(off2, m);
            if (off2 < tol2 || iter >= MAXIT2) break;
            chkcd = CHKIV;
        } else --chkcd;
    }
    // even round count -> final H in Ha, V in Va

    // ---- diag argmin + eigvec extraction ----
    if (t < 16) diagS[t] = Ha[t << 4].x;
    __syncthreads();
    if (t == 0) {
        float best = diagS[0]; int bi_ = 0;
        for (int m = 1; m < 16; ++m) {
            float vv = diagS[m];
            if (vv < best) { best = vv; bi_ = m; }
        }
        midxS = bi_;
    }
    __syncthreads();
    {
        const int mi = midxS;
        if (t < 16) psiS[t] = Va[(t << 4) | (mi ^ t)];
    }
    __syncthreads();

    // ---- loss epilogue: lanes 0..31 each handle one d ----
    float contrib = 0.f;
    if (t < 32) {
        float tr = 0.f, ti = 0.f;
        v2f psi[16];
        for (int jj = 0; jj < 16; ++jj) {
            psi[jj] = psiS[jj];
            tr += psi[jj].x; ti += psi[jj].y;
        }
        float zr = 0.f, zi = 0.f, z2r = 0.f, z2i = 0.f;
        for (int jj = 0; jj < 16; ++jj) {
            float2 cj  = cA [t*16 + jj];
            float2 c2j = cA2[t*16 + jj];
            zr  += cj.x*psi[jj].x  - cj.y*psi[jj].y;
            zi  += cj.x*psi[jj].y  + cj.y*psi[jj].x;
            z2r += c2j.x*psi[jj].x - c2j.y*psi[jj].y;
            z2i += c2j.x*psi[jj].y + c2j.y*psi[jj].x;
        }
        float pos = zr*tr + zi*ti;
        float e2  = z2r*tr + z2i*ti;
        float dx  = pos - xS[t];
        contrib = dx*dx + 0.1f*(e2 - pos*pos);
    }
    for (int off = 32; off > 0; off >>= 1)
        contrib += __shfl_down(contrib, off);
    if (t == 0) atomicAdd(out, contrib * (1.0f/(float)NS));
}

extern "C" void kernel_launch(void* const* d_in, const int* in_sizes, int n_in,
                              void* d_out, int out_size, void* d_ws, size_t ws_size,
                              hipStream_t stream)
{
    const float* A_real = (const float*)d_in[0];
    const float* A_imag = (const float*)d_in[1];
    const float* X      = (const float*)d_in[2];
    float* out = (float*)d_out;

    float2* S   = (float2*)d_ws;          // 32*256
    float2* W   = S  + DC*256;            // 32*256
    float2* cA  = W  + DC*256;            // 32*16
    float2* cA2 = cA + DC*16;             // 32*16
    (void)in_sizes; (void)n_in; (void)out_size; (void)ws_size;

    hipMemsetAsync(d_out, 0, sizeof(float), stream);
    precompute_kernel<<<DC, 256, 0, stream>>>(A_real, A_imag, S, W, cA, cA2);
    energy_kernel<<<NS, 64, 0, stream>>>(X, S, W, cA, cA2, out);
}